// Round 1
// 344.393 us; speedup vs baseline: 1.0031x; 1.0031x over previous
//
#include <hip/hip_runtime.h>
#include <hip/hip_fp16.h>

#define BATCH 4096
#define FIELD 39
#define EMBED 16
#define ROW_F4 (FIELD * EMBED / 4)        // 156 float4 per gathered row (2496 B)
#define TOT_F4 (FIELD * ROW_F4)           // 6084 float4 staged per batch row
#define NPAIRS (FIELD * (FIELD - 1))      // 1482 ordered pairs (i != j)
#define NTASK2 (NPAIRS * 2)               // 2964: 2 lanes per pair
#define BLOCK 1024
#define NWAVES (BLOCK / 64)               // 16
#define SITER ((TOT_F4 + BLOCK - 1) / BLOCK)  // 6
#define CITER ((NTASK2 + BLOCK - 1) / BLOCK)  // 3

// LDS row stride: 39 tiles x 16 halves = 624 halves (1248 B = 78 granules of
// 16 B; 78 mod 8 = 6 -> transposed b128 reads hit only 4 of 8 bank-granule
// positions = ~8-way conflict). Pad +8 halves to 632 (1264 B = 79 granules,
// 79 mod 8 = 7 odd -> all 8 positions walked, max 2-way = free). 16-B aligned.
#define ROW_H 632
#define ROW_H2 (ROW_H / 2)                // 316 half2 per row

// __launch_bounds__(1024, 8): 8 waves/EU -> 32 waves/CU -> 2 blocks/CU
// (LDS 49.3 KB x2 = 98.6 KB < 160 KB). Forces VGPR <= 64.
__global__ __launch_bounds__(BLOCK, 8) void ffm_kernel(
    const int*   __restrict__ idx,    // [B, F]
    const float* __restrict__ vals,   // [B, F]
    const float* __restrict__ emb,    // [100000, F, E]
    const float* __restrict__ w1,     // [100000, 1]
    const float* __restrict__ bias,   // [1]
    float*       __restrict__ out)    // [B, 1]
{
    const int b   = blockIdx.x;
    const int tid = threadIdx.x;

    __shared__ __align__(16) __half s_emb[FIELD * ROW_H];  // 49296 B
    __shared__ float  s_val[FIELD];
    __shared__ float  s_red[NWAVES];

    // ---- Stage: gather addresses come straight from global idx (the 156 B of
    // idx for this block live in ~3 cache lines -> L1 broadcast). No LDS
    // round-trip, no barrier before the gathers can issue.
    const float4* emb4 = (const float4*)emb;
    float4 g[SITER];
    #pragma unroll
    for (int it = 0; it < SITER; ++it) {
        int t  = tid + it * BLOCK;
        int tc = t < TOT_F4 ? t : TOT_F4 - 1;   // clamp: no divergence, dup load benign
        int i  = tc / ROW_F4;
        int o  = tc - i * ROW_F4;
        g[it] = emb4[idx[b * FIELD + i] * ROW_F4 + o];
    }

    // First-order term overlaps the gather latency; s_val pre-scaled by
    // sqrt(0.5) so the pair term is dot * (s_val[i]*s_val[j]) with the 0.5
    // folded in (first-order uses the raw global value).
    float acc = 0.0f;
    if (tid < FIELD) {
        float v = vals[b * FIELD + tid];
        s_val[tid] = v * 0.70710678118654752f;
        acc = v * w1[idx[b * FIELD + tid]];
    }

    __half2* s2 = (__half2*)s_emb;
    #pragma unroll
    for (int it = 0; it < SITER; ++it) {
        int t = tid + it * BLOCK;
        if (t < TOT_F4) {
            int i  = t / ROW_F4;
            int o  = t - i * ROW_F4;
            int p2 = i * ROW_H2 + o * 2;        // padded row base (half2 units)
            s2[p2]     = __floats2half2_rn(g[it].x, g[it].y);
            s2[p2 + 1] = __floats2half2_rn(g[it].z, g[it].w);
        }
    }
    __syncthreads();

    // ---- Pairs from LDS: ordered (i,j), i!=j; 2 lanes/pair, b128 reads.
    // av: stride-1 granules (conflict-free). cv: row stride 79 granules ->
    // every 8 consecutive j cover all 8 bank positions (max 2-way = free).
    #pragma unroll
    for (int it = 0; it < CITER; ++it) {
        int t = tid + it * BLOCK;
        if (t < NTASK2) {
            int p = t >> 1;
            int h = t & 1;                    // which 8-half half of the embedding
            int i = p / (FIELD - 1);
            int r = p - i * (FIELD - 1);
            int j = r + (r >= i ? 1 : 0);
            float4 av = *(const float4*)&s_emb[i * ROW_H + j * EMBED + h * 8];
            float4 cv = *(const float4*)&s_emb[j * ROW_H + i * EMBED + h * 8];
            const __half2* ah = (const __half2*)&av;
            const __half2* ch = (const __half2*)&cv;
            float dot = 0.0f;
            #pragma unroll
            for (int k = 0; k < 4; ++k) {
                float2 a = __half22float2(ah[k]);
                float2 c = __half22float2(ch[k]);
                dot += a.x * c.x + a.y * c.y;
            }
            acc += dot * (s_val[i] * s_val[j]);
        }
    }

    // ---- Reduce: 64-lane wave shuffle, then cross-wave via LDS ----
    #pragma unroll
    for (int off = 32; off > 0; off >>= 1)
        acc += __shfl_down(acc, off, 64);

    const int wave = tid >> 6;
    const int lane = tid & 63;
    if (lane == 0) s_red[wave] = acc;
    __syncthreads();

    if (tid == 0) {
        float s = 0.0f;
        #pragma unroll
        for (int w = 0; w < NWAVES; ++w) s += s_red[w];
        out[b] = s + bias[0];
    }
}

extern "C" void kernel_launch(void* const* d_in, const int* in_sizes, int n_in,
                              void* d_out, int out_size, void* d_ws, size_t ws_size,
                              hipStream_t stream) {
    const int*   idx  = (const int*)d_in[0];
    const float* vals = (const float*)d_in[1];
    const float* emb  = (const float*)d_in[2];
    const float* w1   = (const float*)d_in[3];
    const float* bias = (const float*)d_in[4];
    float* out = (float*)d_out;

    ffm_kernel<<<BATCH, BLOCK, 0, stream>>>(idx, vals, emb, w1, bias, out);
}

// Round 2
// 342.738 us; speedup vs baseline: 1.0079x; 1.0048x over previous
//
#include <hip/hip_runtime.h>
#include <hip/hip_fp16.h>

#define BATCH 4096
#define FIELD 39
#define EMBED 16
#define ROW_F4 (FIELD * EMBED / 4)        // 156 float4 per gathered row (2496 B)
#define TOT_F4 (FIELD * ROW_F4)           // 6084 float4 staged per batch row
#define NPAIRU (FIELD * (FIELD - 1) / 2)  // 741 unordered pairs (i < j)
#define NTASKU (NPAIRU * 2)               // 1482 tasks: 2 lanes per pair (h=0,1)
#define BLOCK 1024
#define NWAVES (BLOCK / 64)               // 16
#define SITER ((TOT_F4 + BLOCK - 1) / BLOCK)  // 6
#define CITER ((NTASKU + BLOCK - 1) / BLOCK)  // 2

// LDS row stride: 39 tiles x 16 halves = 624 halves (1248 B = 78 granules of
// 16 B; 78 mod 8 = 6 -> transposed b128 reads hit only 4 of 8 bank-granule
// positions = ~8-way conflict). Pad +8 halves to 632 (1264 B = 79 granules,
// 79 mod 8 = 7 odd -> all 8 positions walked, max 2-way = free). 16-B aligned.
#define ROW_H 632
#define ROW_H2 (ROW_H / 2)                // 316 half2 per row

typedef _Float16 f16x2 __attribute__((ext_vector_type(2)));

#if defined(__has_builtin) && __has_builtin(__builtin_amdgcn_fdot2)
#define FDOT2(a, b, c) __builtin_amdgcn_fdot2((a), (b), (c), false)
#else
static __device__ __forceinline__ float FDOT2(f16x2 a, f16x2 b, float c) {
    return c + (float)a.x * (float)b.x + (float)a.y * (float)b.y;
}
#endif

// __launch_bounds__(1024, 8): 8 waves/EU -> 32 waves/CU -> 2 blocks/CU
// (LDS 49.3 KB x2 = 98.6 KB < 160 KB). Forces VGPR <= 64.
__global__ __launch_bounds__(BLOCK, 8) void ffm_kernel(
    const int*   __restrict__ idx,    // [B, F]
    const float* __restrict__ vals,   // [B, F]
    const float* __restrict__ emb,    // [100000, F, E]
    const float* __restrict__ w1,     // [100000, 1]
    const float* __restrict__ bias,   // [1]
    float*       __restrict__ out)    // [B, 1]
{
    const int b   = blockIdx.x;
    const int tid = threadIdx.x;

    __shared__ __align__(16) __half s_emb[FIELD * ROW_H];  // 49296 B
    __shared__ float  s_val[FIELD];
    __shared__ float  s_red[NWAVES];

    // ---- Stage: gather addresses come straight from global idx (the 156 B of
    // idx for this block live in ~3 cache lines -> L1 broadcast). No LDS
    // round-trip, no barrier before the gathers can issue.
    const float4* emb4 = (const float4*)emb;
    float4 g[SITER];
    #pragma unroll
    for (int it = 0; it < SITER; ++it) {
        int t  = tid + it * BLOCK;
        int tc = t < TOT_F4 ? t : TOT_F4 - 1;   // clamp: no divergence, dup load benign
        int i  = tc / ROW_F4;
        int o  = tc - i * ROW_F4;
        g[it] = emb4[idx[b * FIELD + i] * ROW_F4 + o];
    }

    // First-order term overlaps the gather latency.
    float acc = 0.0f;
    if (tid < FIELD) {
        float v = vals[b * FIELD + tid];
        s_val[tid] = v;
        acc = v * w1[idx[b * FIELD + tid]];
    }

    __half2* s2 = (__half2*)s_emb;
    #pragma unroll
    for (int it = 0; it < SITER; ++it) {
        int t = tid + it * BLOCK;
        if (t < TOT_F4) {
            int i  = t / ROW_F4;
            int o  = t - i * ROW_F4;
            int p2 = i * ROW_H2 + o * 2;        // padded row base (half2 units)
            s2[p2]     = __floats2half2_rn(g[it].x, g[it].y);  // rn: rtz's bias
            s2[p2 + 1] = __floats2half2_rn(g[it].z, g[it].w);  // would be ~0.3 on out
        }
    }
    __syncthreads();

    // ---- Pairs from LDS: UNORDERED (i<j), each dot computed ONCE (was 2x
    // ordered with 0.5 weight — pure redundancy). 2 lanes/pair (h = which
    // 8-half half), b128 reads, v_dot2_f32_f16 for the dot (f32 accumulate).
    // av: stride-1 granules (conflict-free). cv: row stride 79 granules ->
    // every 8 consecutive j cover all 8 bank positions (max 2-way = free).
    #pragma unroll
    for (int it = 0; it < CITER; ++it) {
        int t = tid + it * BLOCK;
        if (t < NTASKU) {
            int p = t >> 1;
            int h = t & 1;
            // triangular inverse: largest i with tri(i) = i*(77-i)/2 <= p
            int i = (int)((77.0f - sqrtf((float)(5929 - 8 * p))) * 0.5f);
            while (i * (77 - i) / 2 > p) --i;            // fixup (<=1 iter)
            while ((i + 1) * (76 - i) / 2 <= p) ++i;
            int j = i + 1 + (p - i * (77 - i) / 2);
            float4 av = *(const float4*)&s_emb[i * ROW_H + j * EMBED + h * 8];
            float4 cv = *(const float4*)&s_emb[j * ROW_H + i * EMBED + h * 8];
            const f16x2* ah = (const f16x2*)&av;
            const f16x2* ch = (const f16x2*)&cv;
            float dot = 0.0f;
            #pragma unroll
            for (int k = 0; k < 4; ++k)
                dot = FDOT2(ah[k], ch[k], dot);
            acc += dot * (s_val[i] * s_val[j]);
        }
    }

    // ---- Reduce: 64-lane wave shuffle, then cross-wave via LDS ----
    #pragma unroll
    for (int off = 32; off > 0; off >>= 1)
        acc += __shfl_down(acc, off, 64);

    const int wave = tid >> 6;
    const int lane = tid & 63;
    if (lane == 0) s_red[wave] = acc;
    __syncthreads();

    if (tid == 0) {
        float s = 0.0f;
        #pragma unroll
        for (int w = 0; w < NWAVES; ++w) s += s_red[w];
        out[b] = s + bias[0];
    }
}

extern "C" void kernel_launch(void* const* d_in, const int* in_sizes, int n_in,
                              void* d_out, int out_size, void* d_ws, size_t ws_size,
                              hipStream_t stream) {
    const int*   idx  = (const int*)d_in[0];
    const float* vals = (const float*)d_in[1];
    const float* emb  = (const float*)d_in[2];
    const float* w1   = (const float*)d_in[3];
    const float* bias = (const float*)d_in[4];
    float* out = (float*)d_out;

    ffm_kernel<<<BATCH, BLOCK, 0, stream>>>(idx, vals, emb, w1, bias, out);
}